// Round 12
// baseline (89.082 us; speedup 1.0000x reference)
//
#include <hip/hip_runtime.h>

#define N2 4096
#define D 128
#define TAU_INV 10.0f
#define E2SCALE 14.4269504088896340736f   // 10 * log2(e): exp(10x) = exp2(x*E2SCALE)
#define BM 256                    // i-rows per GEMM block (8 waves x 32)
#define BN 256                    // j-cols per GEMM block
#define NT (BN / 32)              // 8 B-tiles per block, shared by all 8 waves
#define GEMM_BLOCKS ((N2 / BM) * (N2 / BN))   // 16*16 = 256 = one per CU
#define NCLS 10
#define CGRP 16                   // row-groups per class
#define CROWS (N2 / CGRP)         // 256 rows per class block
#define CB (NCLS * CGRP)          // 160 class blocks (backfill after GEMM blocks)

typedef __attribute__((ext_vector_type(8))) short bf16x8;
typedef __attribute__((ext_vector_type(16))) float floatx16;

__device__ __forceinline__ short f2bf(float f) {
    unsigned u = __float_as_uint(f);
    u = (u + 0x7fff + ((u >> 16) & 1)) >> 16;   // RNE
    return (short)u;
}
__device__ __forceinline__ float bf2f(short s) {
    return __uint_as_float(((unsigned)(unsigned short)s) << 16);
}

// Normalize rows of p = concat(z_i, z_j) in fp32. Emits TWO layouts:
//   qb  [row][d]                  row-major (class-sum path)
//   qb2 [row/32][k/8][row%32][8]  chunk-major (MFMA fragment loads, lane-contig)
// Also zeroes se_g and block 0 zeroes S/T/CNT.
__global__ __launch_bounds__(64) void prep_kernel(const float* __restrict__ zi,
                                                  const float* __restrict__ zj,
                                                  short* __restrict__ qb,
                                                  short* __restrict__ qb2,
                                                  float* __restrict__ se_g,
                                                  float* __restrict__ S) {
    int row = blockIdx.x;
    int lane = threadIdx.x;                    // 64 lanes, 2 floats each
    const float* src = (row < 2048) ? (zi + row * D) : (zj + (row - 2048) * D);
    float2 v = ((const float2*)src)[lane];
    float ss = v.x * v.x + v.y * v.y;
    #pragma unroll
    for (int m = 1; m < 64; m <<= 1) ss += __shfl_xor(ss, m);
    float inv = 1.0f / sqrtf(ss);              // ||p|| ~ sqrt(128) >> eps
    short2 o;
    o.x = f2bf(v.x * inv);
    o.y = f2bf(v.y * inv);
    ((short2*)(qb + row * D))[lane] = o;
    // chunk-major copy: d0=2*lane -> chunk c=lane>>2, elem e=2*(lane&3)
    int addr2 = (row >> 5) * 4096 + (lane >> 2) * 256 + (row & 31) * 8 + 2 * (lane & 3);
    *(short2*)(qb2 + addr2) = o;
    if (lane == 0) se_g[row] = 0.f;
    if (row == 0)
        for (int k = lane; k < NCLS * D + 2 * NCLS; k += 64) S[k] = 0.f;
}

// Grid = 256 GEMM blocks (FIRST: one per CU, 512 thr) + 160 class blocks.
//
// GEMM block: 256 i-rows x 256 j-cols, 8 waves; wave w owns i-rows
// [rbase, rbase+32). All 8 waves walk the SAME 8 B-tiles IN LOCKSTEP:
// a __syncthreads() at the top of each tile iteration pins all waves'
// loads of tile t into one window, so the 8 requests per line merge in
// the L1 MSHRs (1 fill, 7 hits) instead of drifting apart and re-missing
// (r11 lesson: unsynchronized "reuse" only got 36->27us; B-slice 128KB
// >> 32KB L1). Next tile is register-prefetched right after the barrier
// so the single shared miss overlaps the MFMA chain. Traffic: 33MB chip-
// wide vs r11's 40MB; occupancy 2 waves/SIMD vs 1.
// MFMA 32x32x16 bf16, K=128 (8 steps), fragments lane-contiguous from qb2.
// C/D: col=lane&31, row=(reg&3)+8*(reg>>2)+4*(lane>>5). Accumulates only
// se; the diagonal tile (j0 == rbase) is a wave-uniform branch.
//
// Class block cb (class c, row-group g): masked sums over 256 rows of qb.
// Labels used as VALUES only; all addresses structural -> poison-safe.
__global__ __launch_bounds__(512) void main_kernel(const short* __restrict__ qb,
                                                   const short* __restrict__ qb2,
                                                   const long long* __restrict__ y,
                                                   float* __restrict__ se_g,
                                                   float* __restrict__ S) {
    int tid = threadIdx.x;
    int wave = tid >> 6;
    int lane = tid & 63;

    if (blockIdx.x >= GEMM_BLOCKS) {
        // ---- class-sum path (512 threads: 4 row-groups x 128 dims) ----
        __shared__ float shS[512];
        __shared__ float shT[8];
        __shared__ float shC[4];
        int cb = blockIdx.x - GEMM_BLOCKS;   // 0..159
        int c  = cb / CGRP;                  // 0..9
        int g  = cb % CGRP;                  // 0..15
        int d  = tid & 127;
        int rg = tid >> 7;                   // 0..3
        int r0 = g * CROWS + rg * (CROWS / 4);

        float sS = 0.f, sT = 0.f, cnt = 0.f;
        #pragma unroll 4
        for (int i = 0; i < CROWS / 4; ++i) {
            int r = r0 + i;
            bool m = ((int)y[r & 2047] == c);      // wave-uniform broadcast
            float q = bf2f(qb[r * D + d]);         // coalesced reads
            sS += m ? q : 0.f;
            sT += m ? q * q : 0.f;
            cnt += m ? 1.f : 0.f;
        }

        shS[tid] = sS;
        #pragma unroll
        for (int m = 1; m < 64; m <<= 1) sT += __shfl_xor(sT, m);
        if (lane == 0) shT[wave] = sT;
        if (d == 0) shC[rg] = cnt;
        __syncthreads();
        if (tid < 128)
            atomicAdd(&S[c * D + tid],
                      shS[tid] + shS[tid + 128] + shS[tid + 256] + shS[tid + 384]);
        if (tid == 0) {
            float t8 = 0.f;
            #pragma unroll
            for (int w = 0; w < 8; ++w) t8 += shT[w];
            atomicAdd(&S[NCLS * D + c], t8);                                  // T_c
            atomicAdd(&S[NCLS * D + NCLS + c], shC[0] + shC[1] + shC[2] + shC[3]); // CNT_c
        }
        return;
    }

    // ---- GEMM path ----
    int gb = blockIdx.x;               // 0..255
    int col  = lane & 31;
    int half = lane >> 5;
    int it = gb >> 4;                  // 0..15   (256-row i-block)
    int js = gb & 15;                  // 0..15   (256-col j-slice)
    int rbase = it * BM + wave * 32;   // this wave's 32 i-rows
    int jbase = js * BN;

    // A fragments for this wave's 32 rows: lane-contiguous from qb2
    const short* ap = qb2 + ((rbase >> 5) * 4096) + lane * 8;
    bf16x8 af[8];
    #pragma unroll
    for (int k = 0; k < 8; ++k) af[k] = *(const bf16x8*)(ap + k * 512);

    float se[16];
    #pragma unroll
    for (int r = 0; r < 16; ++r) se[r] = 0.f;

    // prefetch B tile 0
    bf16x8 bf[8];
    {
        const short* bp = qb2 + ((jbase >> 5) * 4096) + lane * 8;
        #pragma unroll
        for (int k = 0; k < 8; ++k) bf[k] = *(const bf16x8*)(bp + k * 512);
    }

    #pragma unroll
    for (int t = 0; t < NT; ++t) {
        int j0 = jbase + t * 32;

        __syncthreads();               // lockstep: all 8 waves on tile t together

        // issue next tile's loads now (misses merge across waves, overlap MFMA)
        bf16x8 bn[8];
        if (t < NT - 1) {
            const short* bp = qb2 + (((j0 + 32) >> 5) * 4096) + lane * 8;
            #pragma unroll
            for (int k = 0; k < 8; ++k) bn[k] = *(const bf16x8*)(bp + k * 512);
        }

        floatx16 acc;
        #pragma unroll
        for (int r = 0; r < 16; ++r) acc[r] = 0.f;
        #pragma unroll
        for (int k = 0; k < 8; ++k)
            acc = __builtin_amdgcn_mfma_f32_32x32x16_bf16(af[k], bf[k], acc, 0, 0, 0);

        if (j0 == rbase) {                    // wave-uniform: diagonal tile
            int jcol = j0 + col;
            #pragma unroll
            for (int r = 0; r < 16; ++r) {
                int rowr = rbase + (r & 3) + 8 * (r >> 2) + 4 * half;
                float e = __builtin_amdgcn_exp2f(acc[r] * E2SCALE);
                se[r] += (rowr == jcol) ? 0.f : e;
            }
        } else {
            #pragma unroll
            for (int r = 0; r < 16; ++r)
                se[r] += __builtin_amdgcn_exp2f(acc[r] * E2SCALE);
        }

        if (t < NT - 1) {
            #pragma unroll
            for (int k = 0; k < 8; ++k) bf[k] = bn[k];
        }
    }

    // reduce across the 32 cols (stay within each 32-lane half), accumulate
    #pragma unroll
    for (int r = 0; r < 16; ++r) {
        float a = se[r];
        #pragma unroll
        for (int m = 1; m < 32; m <<= 1) a += __shfl_xor(a, m);
        if (col == 0) {
            int rowr = rbase + (r & 3) + 8 * (r >> 2) + 4 * half;
            atomicAdd(&se_g[rowr], a);
        }
    }
}

// loss = (sum_i log se_i  -  sum_c 10*(||S_c||^2 - T_c)/(n_c-1)) / N2
__global__ __launch_bounds__(256) void finish_kernel(const float* __restrict__ se_g,
                                                     const float* __restrict__ S,
                                                     float* __restrict__ out) {
    int tid = threadIdx.x;
    int wave = tid >> 6;
    int lane = tid & 63;

    // positive-pair term: wave w handles classes w, w+4, w+8
    float P = 0.f;
    for (int c = wave; c < NCLS; c += 4) {
        float2 sv = ((const float2*)(S + c * D))[lane];
        float s2 = sv.x * sv.x + sv.y * sv.y;
        #pragma unroll
        for (int m = 1; m < 64; m <<= 1) s2 += __shfl_xor(s2, m);
        float n = S[NCLS * D + NCLS + c];
        P += (n >= 2.0f) ? (s2 - S[NCLS * D + c]) * TAU_INV / (n - 1.0f) : 0.f;
    }

    // denominator term
    float L = 0.f;
    for (int i = tid; i < N2; i += 256) L += __logf(se_g[i]);
    #pragma unroll
    for (int m = 1; m < 64; m <<= 1) L += __shfl_xor(L, m);

    __shared__ float red[8];
    if (lane == 0) { red[wave] = L; red[4 + wave] = P; }
    __syncthreads();
    if (tid == 0) {
        float Ls = red[0] + red[1] + red[2] + red[3];
        float Ps = red[4] + red[5] + red[6] + red[7];
        out[0] = (Ls - Ps) * (1.0f / (float)N2);
    }
}

extern "C" void kernel_launch(void* const* d_in, const int* in_sizes, int n_in,
                              void* d_out, int out_size, void* d_ws, size_t ws_size,
                              hipStream_t stream) {
    const float*     zi = (const float*)d_in[0];
    const float*     zj = (const float*)d_in[1];
    const long long* y  = (const long long*)d_in[2];
    float* out = (float*)d_out;

    char* ws = (char*)d_ws;
    short* qb   = (short*)ws;                                  // 1 MB row-major
    short* qb2  = qb + N2 * D;                                 // 1 MB chunk-major
    float* se_g = (float*)(ws + 2 * N2 * D * sizeof(short));   // 16 KB
    float* S    = se_g + N2;                                   // 1300 f32: S/T/CNT

    prep_kernel<<<N2, 64, 0, stream>>>(zi, zj, qb, qb2, se_g, S);
    main_kernel<<<GEMM_BLOCKS + CB, 512, 0, stream>>>(qb, qb2, y, se_g, S);
    finish_kernel<<<1, 256, 0, stream>>>(se_g, S, out);
}

// Round 13
// 88.257 us; speedup vs baseline: 1.0094x; 1.0094x over previous
//
#include <hip/hip_runtime.h>

#define N2 4096
#define D 128
#define TAU_INV 10.0f
#define E2SCALE 14.4269504088896340736f   // 10 * log2(e): exp(10x) = exp2(x*E2SCALE)
#define BM 256                    // i-rows per GEMM block (8 waves x 32)
#define BN 256                    // j-cols per GEMM block (8 tiles x 32, LDS-staged)
#define NT (BN / 32)              // 8 B-tiles per block
#define GEMM_BLOCKS ((N2 / BM) * (N2 / BN))   // 16*16 = 256 = one per CU
#define NCLS 10
#define CGRP 16                   // row-groups per class
#define CROWS (N2 / CGRP)         // 256 rows per class block
#define CB (NCLS * CGRP)          // 160 class blocks (backfill after GEMM blocks)

typedef __attribute__((ext_vector_type(8))) short bf16x8;
typedef __attribute__((ext_vector_type(16))) float floatx16;

__device__ __forceinline__ short f2bf(float f) {
    unsigned u = __float_as_uint(f);
    u = (u + 0x7fff + ((u >> 16) & 1)) >> 16;   // RNE
    return (short)u;
}
__device__ __forceinline__ float bf2f(short s) {
    return __uint_as_float(((unsigned)(unsigned short)s) << 16);
}

// Normalize rows of p = concat(z_i, z_j) in fp32. Emits TWO layouts:
//   qb  [row][d]                  row-major (class-sum path)
//   qb2 [row/32][k/8][row%32][8]  chunk-major: 32-row j-tile = 8KB contiguous,
//                                 so a block's 256-col B-slice is 64KB straight
//                                 memcpy into LDS.
// Also zeroes se_g and block 0 zeroes S/T/CNT.
__global__ __launch_bounds__(64) void prep_kernel(const float* __restrict__ zi,
                                                  const float* __restrict__ zj,
                                                  short* __restrict__ qb,
                                                  short* __restrict__ qb2,
                                                  float* __restrict__ se_g,
                                                  float* __restrict__ S) {
    int row = blockIdx.x;
    int lane = threadIdx.x;                    // 64 lanes, 2 floats each
    const float* src = (row < 2048) ? (zi + row * D) : (zj + (row - 2048) * D);
    float2 v = ((const float2*)src)[lane];
    float ss = v.x * v.x + v.y * v.y;
    #pragma unroll
    for (int m = 1; m < 64; m <<= 1) ss += __shfl_xor(ss, m);
    float inv = 1.0f / sqrtf(ss);              // ||p|| ~ sqrt(128) >> eps
    short2 o;
    o.x = f2bf(v.x * inv);
    o.y = f2bf(v.y * inv);
    ((short2*)(qb + row * D))[lane] = o;
    // chunk-major copy: d0=2*lane -> chunk c=lane>>2, elem e=2*(lane&3)
    int addr2 = (row >> 5) * 4096 + (lane >> 2) * 256 + (row & 31) * 8 + 2 * (lane & 3);
    *(short2*)(qb2 + addr2) = o;
    if (lane == 0) se_g[row] = 0.f;
    if (row == 0)
        for (int k = lane; k < NCLS * D + 2 * NCLS; k += 64) S[k] = 0.f;
}

// Grid = 256 GEMM blocks (FIRST: one per CU, 512 thr) + 160 class blocks.
//
// GEMM block: 256 i-rows x 256 j-cols, 8 waves. The block's whole B-slice
// (64KB, contiguous in qb2) is staged into LDS ONCE by a coalesced block
// copy; after one barrier the entire K-loop runs from ds_read_b128 with
// ZERO global loads. Rationale: the session-stable ~27-36us floor tracked
// the number of per-wave global fragment loads through L1 (r11: 4x fewer
// -> -9us; layout/lockstep/prefetch with same request count -> neutral),
// so the hot loop must stop issuing global loads entirely.
// MFMA 32x32x16 bf16, K=128 (8 steps); A per-wave in registers from qb2.
// C/D: col=lane&31, row=(reg&3)+8*(reg>>2)+4*(lane>>5). Accumulates only
// se; the diagonal tile (j0 == rbase) is a wave-uniform branch.
//
// Class block cb (class c, row-group g): masked sums over 256 rows of qb.
// Labels used as VALUES only; all addresses structural -> poison-safe.
__global__ __launch_bounds__(512) void main_kernel(const short* __restrict__ qb,
                                                   const short* __restrict__ qb2,
                                                   const long long* __restrict__ y,
                                                   float* __restrict__ se_g,
                                                   float* __restrict__ S) {
    int tid = threadIdx.x;
    int wave = tid >> 6;
    int lane = tid & 63;

    if (blockIdx.x >= GEMM_BLOCKS) {
        // ---- class-sum path (512 threads: 4 row-groups x 128 dims) ----
        __shared__ float shS[512];
        __shared__ float shT[8];
        __shared__ float shC[4];
        int cb = blockIdx.x - GEMM_BLOCKS;   // 0..159
        int c  = cb / CGRP;                  // 0..9
        int g  = cb % CGRP;                  // 0..15
        int d  = tid & 127;
        int rg = tid >> 7;                   // 0..3
        int r0 = g * CROWS + rg * (CROWS / 4);

        float sS = 0.f, sT = 0.f, cnt = 0.f;
        #pragma unroll 4
        for (int i = 0; i < CROWS / 4; ++i) {
            int r = r0 + i;
            bool m = ((int)y[r & 2047] == c);      // wave-uniform broadcast
            float q = bf2f(qb[r * D + d]);         // coalesced reads
            sS += m ? q : 0.f;
            sT += m ? q * q : 0.f;
            cnt += m ? 1.f : 0.f;
        }

        shS[tid] = sS;
        #pragma unroll
        for (int m = 1; m < 64; m <<= 1) sT += __shfl_xor(sT, m);
        if (lane == 0) shT[wave] = sT;
        if (d == 0) shC[rg] = cnt;
        __syncthreads();
        if (tid < 128)
            atomicAdd(&S[c * D + tid],
                      shS[tid] + shS[tid + 128] + shS[tid + 256] + shS[tid + 384]);
        if (tid == 0) {
            float t8 = 0.f;
            #pragma unroll
            for (int w = 0; w < 8; ++w) t8 += shT[w];
            atomicAdd(&S[NCLS * D + c], t8);                                  // T_c
            atomicAdd(&S[NCLS * D + NCLS + c], shC[0] + shC[1] + shC[2] + shC[3]); // CNT_c
        }
        return;
    }

    // ---- GEMM path ----
    __shared__ short ldsB[BN * D];     // 32768 shorts = 64 KB, 8 tiles x 8KB
    int gb = blockIdx.x;               // 0..255
    int col  = lane & 31;
    int half = lane >> 5;
    int it = gb >> 4;                  // 0..15   (256-row i-block)
    int js = gb & 15;                  // 0..15   (256-col j-slice)
    int rbase = it * BM + wave * 32;   // this wave's 32 i-rows
    int jbase = js * BN;

    // stage the block's whole B-slice: 64KB contiguous in qb2, coalesced copy
    {
        const bf16x8* src = (const bf16x8*)(qb2 + js * (BN * D));
        bf16x8* dst = (bf16x8*)ldsB;
        #pragma unroll
        for (int i = 0; i < 8; ++i) dst[tid + 512 * i] = src[tid + 512 * i];
    }

    // A fragments for this wave's 32 rows: lane-contiguous from qb2 (overlaps staging)
    const short* ap = qb2 + ((rbase >> 5) * 4096) + lane * 8;
    bf16x8 af[8];
    #pragma unroll
    for (int k = 0; k < 8; ++k) af[k] = *(const bf16x8*)(ap + k * 512);

    float se[16];
    #pragma unroll
    for (int r = 0; r < 16; ++r) se[r] = 0.f;

    __syncthreads();                   // B-slice resident; no further barriers

    const bf16x8* lb = (const bf16x8*)ldsB;
    #pragma unroll
    for (int t = 0; t < NT; ++t) {
        int j0 = jbase + t * 32;

        floatx16 acc;
        #pragma unroll
        for (int r = 0; r < 16; ++r) acc[r] = 0.f;
        #pragma unroll
        for (int k = 0; k < 8; ++k)
            acc = __builtin_amdgcn_mfma_f32_32x32x16_bf16(
                af[k], lb[t * 512 + k * 64 + lane], acc, 0, 0, 0);

        if (j0 == rbase) {                    // wave-uniform: diagonal tile
            int jcol = j0 + col;
            #pragma unroll
            for (int r = 0; r < 16; ++r) {
                int rowr = rbase + (r & 3) + 8 * (r >> 2) + 4 * half;
                float e = __builtin_amdgcn_exp2f(acc[r] * E2SCALE);
                se[r] += (rowr == jcol) ? 0.f : e;
            }
        } else {
            #pragma unroll
            for (int r = 0; r < 16; ++r)
                se[r] += __builtin_amdgcn_exp2f(acc[r] * E2SCALE);
        }
    }

    // reduce across the 32 cols (stay within each 32-lane half), accumulate
    #pragma unroll
    for (int r = 0; r < 16; ++r) {
        float a = se[r];
        #pragma unroll
        for (int m = 1; m < 32; m <<= 1) a += __shfl_xor(a, m);
        if (col == 0) {
            int rowr = rbase + (r & 3) + 8 * (r >> 2) + 4 * half;
            atomicAdd(&se_g[rowr], a);
        }
    }
}

// loss = (sum_i log se_i  -  sum_c 10*(||S_c||^2 - T_c)/(n_c-1)) / N2
__global__ __launch_bounds__(256) void finish_kernel(const float* __restrict__ se_g,
                                                     const float* __restrict__ S,
                                                     float* __restrict__ out) {
    int tid = threadIdx.x;
    int wave = tid >> 6;
    int lane = tid & 63;

    // positive-pair term: wave w handles classes w, w+4, w+8
    float P = 0.f;
    for (int c = wave; c < NCLS; c += 4) {
        float2 sv = ((const float2*)(S + c * D))[lane];
        float s2 = sv.x * sv.x + sv.y * sv.y;
        #pragma unroll
        for (int m = 1; m < 64; m <<= 1) s2 += __shfl_xor(s2, m);
        float n = S[NCLS * D + NCLS + c];
        P += (n >= 2.0f) ? (s2 - S[NCLS * D + c]) * TAU_INV / (n - 1.0f) : 0.f;
    }

    // denominator term
    float L = 0.f;
    for (int i = tid; i < N2; i += 256) L += __logf(se_g[i]);
    #pragma unroll
    for (int m = 1; m < 64; m <<= 1) L += __shfl_xor(L, m);

    __shared__ float red[8];
    if (lane == 0) { red[wave] = L; red[4 + wave] = P; }
    __syncthreads();
    if (tid == 0) {
        float Ls = red[0] + red[1] + red[2] + red[3];
        float Ps = red[4] + red[5] + red[6] + red[7];
        out[0] = (Ls - Ps) * (1.0f / (float)N2);
    }
}

extern "C" void kernel_launch(void* const* d_in, const int* in_sizes, int n_in,
                              void* d_out, int out_size, void* d_ws, size_t ws_size,
                              hipStream_t stream) {
    const float*     zi = (const float*)d_in[0];
    const float*     zj = (const float*)d_in[1];
    const long long* y  = (const long long*)d_in[2];
    float* out = (float*)d_out;

    char* ws = (char*)d_ws;
    short* qb   = (short*)ws;                                  // 1 MB row-major
    short* qb2  = qb + N2 * D;                                 // 1 MB chunk-major
    float* se_g = (float*)(ws + 2 * N2 * D * sizeof(short));   // 16 KB
    float* S    = se_g + N2;                                   // 1300 f32: S/T/CNT

    prep_kernel<<<N2, 64, 0, stream>>>(zi, zj, qb, qb2, se_g, S);
    main_kernel<<<GEMM_BLOCKS + CB, 512, 0, stream>>>(qb, qb2, y, se_g, S);
    finish_kernel<<<1, 256, 0, stream>>>(se_g, S, out);
}